// Round 24
// baseline (85.667 us; speedup 1.0000x reference)
//
#include <hip/hip_runtime.h>
#include <math.h>

#define NN 8192
#define DIM 128
#define NBLK 1024   // (q 0..127) x (p 0..7), stride-8 tile walk

typedef short bf16x8 __attribute__((ext_vector_type(8)));
typedef float f32x4 __attribute__((ext_vector_type(4)));

__device__ inline void gload_lds16(const void* g, void* l) {
    __builtin_amdgcn_global_load_lds((const __attribute__((address_space(1))) void*)g,
                                     (__attribute__((address_space(3))) void*)l, 16, 0, 0);
}

__device__ inline unsigned short f2bf(float x) {
    unsigned u = __float_as_uint(x);
    unsigned r = u + 0x7FFFu + ((u >> 16) & 1u);  // RNE
    return (unsigned short)(r >> 16);
}
__device__ inline float bf2f(unsigned short h) {
    return __uint_as_float(((unsigned)h) << 16);
}

// ---------------------------------------------------------------------------
// Kernel 0: pack mapping into MFMA-fragment-order bf16 chunks AND compute
// exact per-row fp32 sq norms (fused). Also zeroes the completion counter
// (same-stream ordering -> visible to dist; re-zeroed every launch ->
// graph-replay safe, no extra fill dispatch).
// ---------------------------------------------------------------------------
__global__ void pack_kernel(const float* __restrict__ m, unsigned short* __restrict__ buf2,
                            float* __restrict__ sq, unsigned int* __restrict__ counter) {
    const int t = threadIdx.x, l = t & 63;
    const int kq = t >> 6;          // 0..3
    const int g = blockIdx.x;       // 0..511
    if (g == 0 && t == 0) *counter = 0u;
    const int W = g * 4 + kq;
    const int row = g * 16 + (l & 15);
    const int k0 = kq * 32 + (l >> 4) * 8;
    const float* src = m + (size_t)row * DIM + k0;
    float4 v0 = *reinterpret_cast<const float4*>(src);
    float4 v1 = *reinterpret_cast<const float4*>(src + 4);
    float f[8] = {v0.x, v0.y, v0.z, v0.w, v1.x, v1.y, v1.z, v1.w};
    union { ushort4 u4[2]; unsigned short us[8]; } o;
    float s = 0.f;
#pragma unroll
    for (int q = 0; q < 8; ++q) {
        o.us[q] = f2bf(f[q]);
        s += f[q] * f[q];
    }
    unsigned short* dst = buf2 + (size_t)W * 512 + l * 8;
    *reinterpret_cast<ushort4*>(dst) = o.u4[0];
    *reinterpret_cast<ushort4*>(dst + 4) = o.u4[1];

    // row-sum: lanes {x, x+16, x+32, x+48} hold partial sums of row x
    s += __shfl_xor(s, 16, 64);
    s += __shfl_xor(s, 32, 64);
    __shared__ float sqp[4][16];
    if ((l >> 4) == 0) sqp[kq][l & 15] = s;
    __syncthreads();
    if (t < 16) sq[g * 16 + t] = (sqp[0][t] + sqp[1][t]) + (sqp[2][t] + sqp[3][t]);
}

// ---------------------------------------------------------------------------
// Kernel 1: r23 dist kernel (best verified 60.8us), ONE change: final
// reduction fused via completion counter (last block reduces partials in
// fixed order -> deterministic). Producer/consumer/barriers byte-identical.
// ---------------------------------------------------------------------------
__global__ __launch_bounds__(512, 6) void dist_kernel(const unsigned short* __restrict__ buf2,
                                                      const float* __restrict__ D,
                                                      const float* __restrict__ sq,
                                                      float* __restrict__ partials,
                                                      unsigned int* __restrict__ counter,
                                                      float* __restrict__ out) {
    __shared__ __align__(16) char Bbuf[2][16384];      // 32 KB (aliased by final reduce)
    __shared__ __align__(16) char dtile[2][64 * 144];  // 18.4 KB
    __shared__ float wred[8];
    __shared__ int islast;

    const int t = threadIdx.x, l = t & 63, w = t >> 6;
    const int b = blockIdx.x;
    const int q = b >> 3, p = b & 7;
    const int cj0 = q + p;
    float psum = 0.f;

    if (cj0 < 128) {
        const int nt = ((127 - cj0) >> 3) + 1;   // 1..16
        const int l15 = l & 15, hi = l >> 4;
        const int colq = hi * 4;
        const int strip = w & 3;
        const int i_row = q * 64 + strip * 16 + l15;
        const int ldsoff = (strip * 16 + l15) * 144 + hi * 8;

        if (w < 4) {
            // ========================= PRODUCER =========================
            bf16x8 af[4];
#pragma unroll
            for (int kq = 0; kq < 4; ++kq)
                af[kq] = *(const bf16x8*)(buf2 + (size_t)((q * 4 + strip) * 4 + kq) * 512 + l * 8);
            const float sa = sq[i_row];

            f32x4 csb[4], nsb[4];
#pragma unroll
            for (int s = 0; s < 4; ++s)
                csb[s] = *(const f32x4*)(sq + cj0 * 64 + s * 16 + colq);
#pragma unroll
            for (int kq = 0; kq < 4; ++kq)
                gload_lds16(buf2 + (size_t)((cj0 * 4 + strip) * 4 + kq) * 512 + l * 8,
                            (void*)&Bbuf[0][(strip * 4 + kq) * 1024]);
            asm volatile("s_waitcnt vmcnt(0)" ::: "memory");
            __builtin_amdgcn_s_barrier();   // #0

            for (int tt = 0; tt < nt; ++tt) {
                const int slot = tt & 1;
                if (tt + 1 < nt) {
                    const int ncj = cj0 + (tt + 1) * 8;
#pragma unroll
                    for (int s = 0; s < 4; ++s)
                        nsb[s] = *(const f32x4*)(sq + ncj * 64 + s * 16 + colq);
#pragma unroll
                    for (int kq = 0; kq < 4; ++kq)
                        gload_lds16(buf2 + (size_t)((ncj * 4 + strip) * 4 + kq) * 512 + l * 8,
                                    (void*)&Bbuf[slot ^ 1][(strip * 4 + kq) * 1024]);
                }
#pragma unroll
                for (int s = 0; s < 4; ++s) {
                    bf16x8 bfr[4];
#pragma unroll
                    for (int kq = 0; kq < 4; ++kq)
                        bfr[kq] = *(const bf16x8*)&Bbuf[slot][(s * 4 + kq) * 1024 + l * 16];
                    f32x4 acc = {};
#pragma unroll
                    for (int kq = 0; kq < 4; ++kq)
                        acc = __builtin_amdgcn_mfma_f32_16x16x32_bf16(bfr[kq], af[kq], acc, 0, 0, 0);
                    ushort4 o;
                    unsigned short* op = (unsigned short*)&o;
#pragma unroll
                    for (int r = 0; r < 4; ++r) {
                        float d2 = fmaf(-2.f, acc[r], sa + csb[s][r]);
                        op[r] = f2bf(sqrtf(fmaxf(d2, 0.f)));
                    }
                    *reinterpret_cast<ushort4*>(&dtile[slot][0] + ldsoff + s * 32) = o;
                }
                asm volatile("s_waitcnt vmcnt(0) lgkmcnt(0)" ::: "memory");
                __builtin_amdgcn_sched_barrier(0);
                __builtin_amdgcn_s_barrier();   // #tt+1
                if (tt + 1 < nt) {
#pragma unroll
                    for (int s = 0; s < 4; ++s) csb[s] = nsb[s];
                }
            }
        } else {
            // ========================= CONSUMER =========================
            const float* Drow = D + (size_t)i_row * NN;

            auto consume = [&](int tile, const f32x4(&dc)[4]) {
                const int cj = cj0 + tile * 8;
                const char* slot = &dtile[tile & 1][0];
                if (cj != q) {
#pragma unroll
                    for (int s = 0; s < 4; ++s) {
                        ushort4 o = *reinterpret_cast<const ushort4*>(slot + ldsoff + s * 32);
                        const unsigned short* op = (const unsigned short*)&o;
#pragma unroll
                        for (int r = 0; r < 4; ++r) {
                            float Dv = dc[s][r];
                            psum += __fdividef(fabsf(bf2f(op[r]) - Dv), Dv);
                        }
                    }
                } else {
#pragma unroll
                    for (int s = 0; s < 4; ++s) {
                        ushort4 o = *reinterpret_cast<const ushort4*>(slot + ldsoff + s * 32);
                        const unsigned short* op = (const unsigned short*)&o;
#pragma unroll
                        for (int r = 0; r < 4; ++r) {
                            const int j = cj * 64 + s * 16 + colq + r;
                            if (j > i_row) {
                                float Dv = dc[s][r];
                                psum += __fdividef(fabsf(bf2f(op[r]) - Dv), Dv);
                            }
                        }
                    }
                }
            };

            f32x4 dA[4], dB[4];
#pragma unroll
            for (int s = 0; s < 4; ++s)
                dA[s] = *(const f32x4*)(Drow + cj0 * 64 + s * 16 + colq);
            __builtin_amdgcn_s_barrier();   // #0

            bool cur_a = true;
            for (int tt = 0; tt < nt; ++tt) {
                if (tt + 1 < nt) {
                    const int ncj = cj0 + (tt + 1) * 8;
                    if (cur_a) {
#pragma unroll
                        for (int s = 0; s < 4; ++s)
                            dB[s] = *(const f32x4*)(Drow + ncj * 64 + s * 16 + colq);
                    } else {
#pragma unroll
                        for (int s = 0; s < 4; ++s)
                            dA[s] = *(const f32x4*)(Drow + ncj * 64 + s * 16 + colq);
                    }
                }
                __builtin_amdgcn_s_barrier();   // #tt+1: dtile(tt) ready
                if (cur_a) consume(tt, dA);
                else       consume(tt, dB);
                cur_a = !cur_a;
            }
        }
    }

    // ---- deterministic block reduction (producers contribute 0) ----
    for (int off = 32; off > 0; off >>= 1) psum += __shfl_down(psum, off, 64);
    __syncthreads();
    if (l == 0) wred[w] = psum;
    __syncthreads();
    if (t == 0) {
        float s = 0.f;
#pragma unroll
        for (int k = 0; k < 8; ++k) s += wred[k];
        partials[b] = 2.f * s;
        __threadfence();
        unsigned int old = atomicAdd(counter, 1u);
        islast = (old == NBLK - 1);
    }
    __syncthreads();

    // ---- last block: deterministic final reduction (aliases dead Bbuf) ----
    if (islast) {
        __threadfence();
        double* red = (double*)&Bbuf[0][0];
        double s = 0.0;
        for (int i = t; i < NBLK; i += 512) s += (double)partials[i];
        red[t] = s;
        __syncthreads();
        for (int off = 256; off > 0; off >>= 1) {
            if (t < off) red[t] += red[t + off];
            __syncthreads();
        }
        if (t == 0) out[0] = (float)(red[0] / ((double)NN * (double)NN - (double)NN));
    }
}

// ---------------------------------------------------------------------------
extern "C" void kernel_launch(void* const* d_in, const int* in_sizes, int n_in,
                              void* d_out, int out_size, void* d_ws, size_t ws_size,
                              hipStream_t stream) {
    const float* mapping = (const float*)d_in[0];
    const float* D       = (const float*)d_in[1];
    float* out = (float*)d_out;

    unsigned short* buf2 = (unsigned short*)d_ws;        // 2 MiB
    float* sq            = (float*)(buf2 + NN * DIM);    // NN floats
    float* partials      = sq + NN;                      // NBLK floats
    unsigned int* counter = (unsigned int*)(partials + NBLK);

    pack_kernel<<<512, 256, 0, stream>>>(mapping, buf2, sq, counter);
    dist_kernel<<<NBLK, 512, 0, stream>>>(buf2, D, sq, partials, counter, out);
}

// Round 25
// 60.199 us; speedup vs baseline: 1.4231x; 1.4231x over previous
//
#include <hip/hip_runtime.h>
#include <math.h>

#define NN 8192
#define DIM 128
#define NBLK 1024   // (q 0..127) x (p 0..7), stride-8 tile walk

typedef short bf16x8 __attribute__((ext_vector_type(8)));
typedef float f32x4 __attribute__((ext_vector_type(4)));

__device__ inline void gload_lds16(const void* g, void* l) {
    __builtin_amdgcn_global_load_lds((const __attribute__((address_space(1))) void*)g,
                                     (__attribute__((address_space(3))) void*)l, 16, 0, 0);
}

__device__ inline unsigned short f2bf(float x) {
    unsigned u = __float_as_uint(x);
    unsigned r = u + 0x7FFFu + ((u >> 16) & 1u);  // RNE
    return (unsigned short)(r >> 16);
}
__device__ inline float bf2f(unsigned short h) {
    return __uint_as_float(((unsigned)h) << 16);
}

// ---------------------------------------------------------------------------
// Kernel 0: pack mapping into MFMA-fragment-order bf16 chunks AND compute
// exact per-row fp32 sq norms (fused, deterministic fixed-order reduction).
// Block g = rows 16g..16g+15; wave kq covers k-cols kq*32..+31.
// ---------------------------------------------------------------------------
__global__ void pack_kernel(const float* __restrict__ m, unsigned short* __restrict__ buf2,
                            float* __restrict__ sq) {
    const int t = threadIdx.x, l = t & 63;
    const int kq = t >> 6;          // 0..3
    const int g = blockIdx.x;       // 0..511
    const int W = g * 4 + kq;
    const int row = g * 16 + (l & 15);
    const int k0 = kq * 32 + (l >> 4) * 8;
    const float* src = m + (size_t)row * DIM + k0;
    float4 v0 = *reinterpret_cast<const float4*>(src);
    float4 v1 = *reinterpret_cast<const float4*>(src + 4);
    float f[8] = {v0.x, v0.y, v0.z, v0.w, v1.x, v1.y, v1.z, v1.w};
    union { ushort4 u4[2]; unsigned short us[8]; } o;
    float s = 0.f;
#pragma unroll
    for (int q = 0; q < 8; ++q) {
        o.us[q] = f2bf(f[q]);
        s += f[q] * f[q];
    }
    unsigned short* dst = buf2 + (size_t)W * 512 + l * 8;
    *reinterpret_cast<ushort4*>(dst) = o.u4[0];
    *reinterpret_cast<ushort4*>(dst + 4) = o.u4[1];

    // row-sum: lanes {x, x+16, x+32, x+48} hold partial sums of row x
    s += __shfl_xor(s, 16, 64);
    s += __shfl_xor(s, 32, 64);
    __shared__ float sqp[4][16];
    if ((l >> 4) == 0) sqp[kq][l & 15] = s;
    __syncthreads();
    if (t < 16) sq[g * 16 + t] = (sqp[0][t] + sqp[1][t]) + (sqp[2][t] + sqp[3][t]);
}

// ---------------------------------------------------------------------------
// Kernel 1: r23 dist kernel (best verified: 60.8us total).
// P/C waves, B staged once per block via global_load_lds (dbuf), producer
// computes d=sqrt(...) -> bf16 dtile ring; consumer pure-D FIFO, 1-deep
// double buffer; barrier-per-tile protocol.
// ---------------------------------------------------------------------------
__global__ __launch_bounds__(512, 6) void dist_kernel(const unsigned short* __restrict__ buf2,
                                                      const float* __restrict__ D,
                                                      const float* __restrict__ sq,
                                                      float* __restrict__ partials) {
    __shared__ __align__(16) char Bbuf[2][16384];      // 32 KB
    __shared__ __align__(16) char dtile[2][64 * 144];  // 18.4 KB
    __shared__ float wred[8];

    const int t = threadIdx.x, l = t & 63, w = t >> 6;
    const int b = blockIdx.x;
    const int q = b >> 3, p = b & 7;
    const int cj0 = q + p;
    float psum = 0.f;

    if (cj0 < 128) {
        const int nt = ((127 - cj0) >> 3) + 1;   // 1..16
        const int l15 = l & 15, hi = l >> 4;
        const int colq = hi * 4;
        const int strip = w & 3;
        const int i_row = q * 64 + strip * 16 + l15;
        const int ldsoff = (strip * 16 + l15) * 144 + hi * 8;

        if (w < 4) {
            // ========================= PRODUCER =========================
            bf16x8 af[4];
#pragma unroll
            for (int kq = 0; kq < 4; ++kq)
                af[kq] = *(const bf16x8*)(buf2 + (size_t)((q * 4 + strip) * 4 + kq) * 512 + l * 8);
            const float sa = sq[i_row];

            f32x4 csb[4], nsb[4];
#pragma unroll
            for (int s = 0; s < 4; ++s)
                csb[s] = *(const f32x4*)(sq + cj0 * 64 + s * 16 + colq);
#pragma unroll
            for (int kq = 0; kq < 4; ++kq)
                gload_lds16(buf2 + (size_t)((cj0 * 4 + strip) * 4 + kq) * 512 + l * 8,
                            (void*)&Bbuf[0][(strip * 4 + kq) * 1024]);
            asm volatile("s_waitcnt vmcnt(0)" ::: "memory");
            __builtin_amdgcn_s_barrier();   // #0

            for (int tt = 0; tt < nt; ++tt) {
                const int slot = tt & 1;
                if (tt + 1 < nt) {
                    const int ncj = cj0 + (tt + 1) * 8;
#pragma unroll
                    for (int s = 0; s < 4; ++s)
                        nsb[s] = *(const f32x4*)(sq + ncj * 64 + s * 16 + colq);
#pragma unroll
                    for (int kq = 0; kq < 4; ++kq)
                        gload_lds16(buf2 + (size_t)((ncj * 4 + strip) * 4 + kq) * 512 + l * 8,
                                    (void*)&Bbuf[slot ^ 1][(strip * 4 + kq) * 1024]);
                }
#pragma unroll
                for (int s = 0; s < 4; ++s) {
                    bf16x8 bfr[4];
#pragma unroll
                    for (int kq = 0; kq < 4; ++kq)
                        bfr[kq] = *(const bf16x8*)&Bbuf[slot][(s * 4 + kq) * 1024 + l * 16];
                    f32x4 acc = {};
#pragma unroll
                    for (int kq = 0; kq < 4; ++kq)
                        acc = __builtin_amdgcn_mfma_f32_16x16x32_bf16(bfr[kq], af[kq], acc, 0, 0, 0);
                    ushort4 o;
                    unsigned short* op = (unsigned short*)&o;
#pragma unroll
                    for (int r = 0; r < 4; ++r) {
                        float d2 = fmaf(-2.f, acc[r], sa + csb[s][r]);
                        op[r] = f2bf(sqrtf(fmaxf(d2, 0.f)));
                    }
                    *reinterpret_cast<ushort4*>(&dtile[slot][0] + ldsoff + s * 32) = o;
                }
                asm volatile("s_waitcnt vmcnt(0) lgkmcnt(0)" ::: "memory");
                __builtin_amdgcn_sched_barrier(0);
                __builtin_amdgcn_s_barrier();   // #tt+1
                if (tt + 1 < nt) {
#pragma unroll
                    for (int s = 0; s < 4; ++s) csb[s] = nsb[s];
                }
            }
        } else {
            // ========================= CONSUMER =========================
            const float* Drow = D + (size_t)i_row * NN;

            auto consume = [&](int tile, const f32x4(&dc)[4]) {
                const int cj = cj0 + tile * 8;
                const char* slot = &dtile[tile & 1][0];
                if (cj != q) {
#pragma unroll
                    for (int s = 0; s < 4; ++s) {
                        ushort4 o = *reinterpret_cast<const ushort4*>(slot + ldsoff + s * 32);
                        const unsigned short* op = (const unsigned short*)&o;
#pragma unroll
                        for (int r = 0; r < 4; ++r) {
                            float Dv = dc[s][r];
                            psum += __fdividef(fabsf(bf2f(op[r]) - Dv), Dv);
                        }
                    }
                } else {
#pragma unroll
                    for (int s = 0; s < 4; ++s) {
                        ushort4 o = *reinterpret_cast<const ushort4*>(slot + ldsoff + s * 32);
                        const unsigned short* op = (const unsigned short*)&o;
#pragma unroll
                        for (int r = 0; r < 4; ++r) {
                            const int j = cj * 64 + s * 16 + colq + r;
                            if (j > i_row) {
                                float Dv = dc[s][r];
                                psum += __fdividef(fabsf(bf2f(op[r]) - Dv), Dv);
                            }
                        }
                    }
                }
            };

            f32x4 dA[4], dB[4];
#pragma unroll
            for (int s = 0; s < 4; ++s)
                dA[s] = *(const f32x4*)(Drow + cj0 * 64 + s * 16 + colq);
            __builtin_amdgcn_s_barrier();   // #0

            bool cur_a = true;
            for (int tt = 0; tt < nt; ++tt) {
                if (tt + 1 < nt) {
                    const int ncj = cj0 + (tt + 1) * 8;
                    if (cur_a) {
#pragma unroll
                        for (int s = 0; s < 4; ++s)
                            dB[s] = *(const f32x4*)(Drow + ncj * 64 + s * 16 + colq);
                    } else {
#pragma unroll
                        for (int s = 0; s < 4; ++s)
                            dA[s] = *(const f32x4*)(Drow + ncj * 64 + s * 16 + colq);
                    }
                }
                __builtin_amdgcn_s_barrier();   // #tt+1: dtile(tt) ready
                if (cur_a) consume(tt, dA);
                else       consume(tt, dB);
                cur_a = !cur_a;
            }
        }
    }

    // ---- deterministic block reduction (producers contribute 0) ----
    for (int off = 32; off > 0; off >>= 1) psum += __shfl_down(psum, off, 64);
    __syncthreads();
    if (l == 0) wred[w] = psum;
    __syncthreads();
    if (t == 0) {
        float s = 0.f;
#pragma unroll
        for (int k = 0; k < 8; ++k) s += wred[k];
        partials[b] = 2.f * s;
    }
}

// ---------------------------------------------------------------------------
// Kernel 2: deterministic final reduction
// ---------------------------------------------------------------------------
__global__ void reduce_kernel(const float* __restrict__ partials, float* __restrict__ out) {
    __shared__ double sm[256];
    const int t = threadIdx.x;
    double s = 0.0;
    for (int i = t; i < NBLK; i += 256) s += (double)partials[i];
    sm[t] = s;
    __syncthreads();
    for (int off = 128; off > 0; off >>= 1) {
        if (t < off) sm[t] += sm[t + off];
        __syncthreads();
    }
    if (t == 0) out[0] = (float)(sm[0] / ((double)NN * (double)NN - (double)NN));
}

// ---------------------------------------------------------------------------
extern "C" void kernel_launch(void* const* d_in, const int* in_sizes, int n_in,
                              void* d_out, int out_size, void* d_ws, size_t ws_size,
                              hipStream_t stream) {
    const float* mapping = (const float*)d_in[0];
    const float* D       = (const float*)d_in[1];
    float* out = (float*)d_out;

    unsigned short* buf2 = (unsigned short*)d_ws;        // 2 MiB
    float* sq            = (float*)(buf2 + NN * DIM);    // NN floats
    float* partials      = sq + NN;                      // NBLK floats

    pack_kernel<<<512, 256, 0, stream>>>(mapping, buf2, sq);
    dist_kernel<<<NBLK, 512, 0, stream>>>(buf2, D, sq, partials);
    reduce_kernel<<<1, 256, 0, stream>>>(partials, out);
}